// Round 6
// baseline (6142.486 us; speedup 1.0000x reference)
//
#include <hip/hip_runtime.h>
#include <hip/hip_cooperative_groups.h>

namespace cg = cooperative_groups;

#define NT 499    // T-1 sequential steps
#define NB 64     // batch (= wave size, lane = b)
#define NN 512    // region width
#define ND 100    // input dim
#define NO 10     // output dim
#define NWAVE 16  // waves per WG (1024 threads) -> 4 waves/SIMD
#define KW 32     // k-slice width per wave (16*32 = 512)
#define NWG 256

// workspace layout (floats)
#define XT_SZ   (NT * ND * NB)     // XT[t][d][b] = X[t+1][b][d]
#define RBUF_SZ (2 * NN * NB)      // double-buffered rT[buf][n][b]
#define XT_OFF  0
#define RM_OFF  (XT_OFF + XT_SZ)
#define RP_OFF  (RM_OFF + RBUF_SZ)
#define RS_OFF  (RP_OFF + RBUF_SZ)
#define FLAG_OFF (RS_OFF + RBUF_SZ)   // word 0 = barrier counter

// sc write-through store: publishes r to the coherence point directly, so NO
// release fence (buffer_wbl2 drain) is needed anywhere (R2/R3/R4-proven:
// __syncthreads' vmcnt(0) drains these before the barrier add issues).
__device__ __forceinline__ void st_cg(float* p, float v) {
  __hip_atomic_store(p, v, __ATOMIC_RELAXED, __HIP_MEMORY_SCOPE_AGENT);
}

// Transpose X[t+1][b][d] -> XT[t][d][b] so the main loop's lane=b loads coalesce.
__global__ void xpose_kernel(const float* __restrict__ X, float* __restrict__ XT) {
  __shared__ float tile[NB * ND];
  const int t = blockIdx.x;
  const float* src = X + (size_t)(t + 1) * NB * ND;
  for (int i = threadIdx.x; i < NB * ND; i += blockDim.x) tile[i] = src[i];
  __syncthreads();
  float* dst = XT + (size_t)t * ND * NB;
  for (int i = threadIdx.x; i < NB * ND; i += blockDim.x) {
    const int d = i >> 6, b = i & 63;
    dst[i] = tile[b * ND + d];
  }
}

// Persistent cooperative kernel: 256 WGs x 1024 threads (16 waves = 4/SIMD).
// R6 = R5 with the output off-by-one fixed:
//   window at iteration ti computes r_{ti-1}·W_out (reads r_m1[cur]);
//   that is out[ti-1], reduced+stored at iteration ti+1 -> index ti-2 there.
//   Epilogue: out[NT-2] from last window's red, out[NT-1] from final r_m1.
__global__ void __launch_bounds__(1024)
rnn_kernel(const float* __restrict__ XT,
           float* __restrict__ r_m1, float* __restrict__ r_pmd, float* __restrict__ r_s1,
           const float* __restrict__ W_rec_m1, const float* __restrict__ W_rec_pmd,
           const float* __restrict__ W_rec_s1,
           const float* __restrict__ b_m1, const float* __restrict__ b_pmd,
           const float* __restrict__ b_s1,
           const float* __restrict__ W_pmd_m1, const float* __restrict__ W_s1_m1,
           const float* __restrict__ W_m1_pmd, const float* __restrict__ W_in_pmd,
           const float* __restrict__ W_in_s1, const float* __restrict__ W_out,
           float* __restrict__ out,
           unsigned* __restrict__ flags, unsigned* __restrict__ gen)
{
  (void)gen;
  unsigned* cnt = flags;   // single barrier counter, monotonic over steps
  const int g    = blockIdx.x;
  const int wave = __builtin_amdgcn_readfirstlane((int)threadIdx.x >> 6);
  const int lane = (int)threadIdx.x & 63;
  const int n0 = 2 * g, n1 = 2 * g + 1;
  const int k0 = __builtin_amdgcn_readfirstlane(wave * KW);
  const int d0 = __builtin_amdgcn_readfirstlane(wave * 7);   // 16*7=112 covers ND=100
  int dlen = ND - d0; dlen = dlen < 0 ? 0 : (dlen > 7 ? 7 : dlen);
  const bool has_out = (g < NO);

  __shared__ float red[NWAVE][7][64];   // 28 KB; slot 6 = window-phase ao partials

  // ws is poisoned before every launch: zero r slot 0 and the counter.
  for (int i = g * (int)blockDim.x + (int)threadIdx.x; i < NN * NB;
       i += (int)(gridDim.x * blockDim.x)) {
    r_m1[i] = 0.f; r_pmd[i] = 0.f; r_s1[i] = 0.f;
  }
  if (g == 0 && threadIdx.x == 0) *cnt = 0u;

  // wave-uniform weight row pointers -> scalar loads (K$-resident)
  const float* wrm0 = W_rec_m1 + (size_t)n0 * NN + k0;
  const float* wrm1 = W_rec_m1 + (size_t)n1 * NN + k0;
  const float* wmp0 = W_m1_pmd + (size_t)n0 * NN + k0;
  const float* wmp1 = W_m1_pmd + (size_t)n1 * NN + k0;
  const float* wpm0 = W_pmd_m1 + (size_t)n0 * NN + k0;
  const float* wpm1 = W_pmd_m1 + (size_t)n1 * NN + k0;
  const float* wrp0 = W_rec_pmd + (size_t)n0 * NN + k0;
  const float* wrp1 = W_rec_pmd + (size_t)n1 * NN + k0;
  const float* wsm0 = W_s1_m1 + (size_t)n0 * NN + k0;
  const float* wsm1 = W_s1_m1 + (size_t)n1 * NN + k0;
  const float* wrs0 = W_rec_s1 + (size_t)n0 * NN + k0;
  const float* wrs1 = W_rec_s1 + (size_t)n1 * NN + k0;
  const float* wip0 = W_in_pmd + (size_t)n0 * ND + d0;
  const float* wip1 = W_in_pmd + (size_t)n1 * ND + d0;
  const float* wis0 = W_in_s1 + (size_t)n0 * ND + d0;
  const float* wis1 = W_in_s1 + (size_t)n1 * ND + d0;
  const float* wo   = W_out + (size_t)(has_out ? g : 0) * NN + k0;

  // publish role: wave j<6 owns x-state target j; wave 6 reduces out
  float* pubBase = nullptr; float bP = 0.f;
  if (wave == 0)      { pubBase = r_m1  + n0 * NB; bP = b_m1[n0]; }
  else if (wave == 1) { pubBase = r_m1  + n1 * NB; bP = b_m1[n1]; }
  else if (wave == 2) { pubBase = r_pmd + n0 * NB; bP = b_pmd[n0]; }
  else if (wave == 3) { pubBase = r_pmd + n1 * NB; bP = b_pmd[n1]; }
  else if (wave == 4) { pubBase = r_s1  + n0 * NB; bP = b_s1[n0]; }
  else if (wave == 5) { pubBase = r_s1  + n1 * NB; bP = b_s1[n1]; }
  float xP = 0.f;   // per-wave persistent x-state (lane = b)

  // X-part accumulators for the upcoming step (computed during barrier wait)
  float apX0 = 0.f, apX1 = 0.f, asX0 = 0.f, asX1 = 0.f;
  {
    const float* xt = XT + d0 * NB + lane;   // ti = 0
    for (int d = 0; d < dlen; ++d) {
      const float v = xt[d * NB];
      apX0 = fmaf(v, wip0[d], apX0);
      apX1 = fmaf(v, wip1[d], apX1);
      asX0 = fmaf(v, wis0[d], asX0);
      asX1 = fmaf(v, wis1[d], asX1);
    }
  }

  // one-time heavyweight sync to order init (cnt/r zeroing) grid-wide
  cg::this_grid().sync();

  for (int ti = 0; ti < NT; ++ti) {
    const int cur = ti & 1, nxt = cur ^ 1;
    const float* rm = r_m1 + cur * NN * NB + k0 * NB + lane;
    const float* rp = r_pmd + cur * NN * NB + k0 * NB + lane;
    const float* rs = r_s1 + cur * NN * NB + k0 * NB + lane;
    float am0 = 0.f, am1 = 0.f;
    float ap0 = apX0, ap1 = apX1, as0 = asX0, as1 = asX1;

    // source r_m1 -> m1(rec), pmd(m1->pmd)   [W_out pass lives in the window]
    #pragma unroll
    for (int k = 0; k < KW; ++k) {
      const float v = rm[k * NB];
      am0 = fmaf(v, wrm0[k], am0);
      am1 = fmaf(v, wrm1[k], am1);
      ap0 = fmaf(v, wmp0[k], ap0);
      ap1 = fmaf(v, wmp1[k], ap1);
    }
    // source r_pmd -> m1(pmd->m1), pmd(rec)
    #pragma unroll
    for (int k = 0; k < KW; ++k) {
      const float v = rp[k * NB];
      am0 = fmaf(v, wpm0[k], am0);
      am1 = fmaf(v, wpm1[k], am1);
      ap0 = fmaf(v, wrp0[k], ap0);
      ap1 = fmaf(v, wrp1[k], ap1);
    }
    // source r_s1 -> m1(s1->m1), s1(rec)
    #pragma unroll
    for (int k = 0; k < KW; ++k) {
      const float v = rs[k * NB];
      am0 = fmaf(v, wsm0[k], am0);
      am1 = fmaf(v, wsm1[k], am1);
      as0 = fmaf(v, wrs0[k], as0);
      as1 = fmaf(v, wrs1[k], as1);
    }

    red[wave][0][lane] = am0; red[wave][1][lane] = am1;
    red[wave][2][lane] = ap0; red[wave][3][lane] = ap1;
    red[wave][4][lane] = as0; red[wave][5][lane] = as1;
    __syncthreads();

    // publish: wave j<6 reduces its x-target; wave 6 reduces the red[.][6]
    // written during iteration ti-1's window = r_{ti-2}·W_out = out[ti-2].
    if (wave < 6) {
      float s = red[0][wave][lane];
      #pragma unroll
      for (int w = 1; w < NWAVE; ++w) s += red[w][wave][lane];
      xP = 0.9f * xP + 0.1f * (s + bP);
      st_cg(pubBase + nxt * NN * NB + lane, tanhf(xP));
    } else if (wave == 6 && has_out && ti >= 2) {
      float s = red[0][6][lane];
      #pragma unroll
      for (int w = 1; w < NWAVE; ++w) s += red[w][6][lane];
      out[(size_t)(ti - 2) * (NB * NO) + lane * NO + g] = s;
    }

    // ---- single-hop counter barrier. __syncthreads drains the sc r-stores
    // (vmcnt(0) before s_barrier), so the fetch_add is ordered behind them. ----
    __syncthreads();
    const unsigned tgtc = (unsigned)(ti + 1) * (unsigned)NWG;
    if (threadIdx.x == 0) {
      __hip_atomic_fetch_add(cnt, 1u, __ATOMIC_RELAXED, __HIP_MEMORY_SCOPE_AGENT);
    }

    // ---- barrier-wait window: work that only needs CURRENT-step data ----
    // (a) X-part of step ti+1 (static XT/W_in)
    apX0 = 0.f; apX1 = 0.f; asX0 = 0.f; asX1 = 0.f;
    if (ti + 1 < NT) {
      const float* xt = XT + (size_t)(ti + 1) * ND * NB + d0 * NB + lane;
      for (int d = 0; d < dlen; ++d) {
        const float v = xt[d * NB];
        apX0 = fmaf(v, wip0[d], apX0);
        apX1 = fmaf(v, wip1[d], apX1);
        asX0 = fmaf(v, wis0[d], asX0);
        asX1 = fmaf(v, wis1[d], asX1);
      }
    }
    // (b) W_out pass over r_m1[cur] = r_{ti-1} -> out[ti-1] partials.
    // Safe vs next-step publishes into this buffer: writers must clear the
    // barrier AND run their full main phase (~5us) first; this read completes
    // ~1.5us after our own add.
    if (has_out) {
      float ao = 0.f;
      #pragma unroll
      for (int k = 0; k < KW; ++k) ao = fmaf(rm[k * NB], wo[k], ao);
      red[wave][6][lane] = ao;
    }

    if (threadIdx.x == 0) {
      while (__hip_atomic_load(cnt, __ATOMIC_RELAXED,
                               __HIP_MEMORY_SCOPE_AGENT) < tgtc)
        __builtin_amdgcn_s_sleep(1);
      __builtin_amdgcn_fence(__ATOMIC_ACQUIRE, "agent");   // acquire-only inv
    }
    __syncthreads();
  }

  // epilogue (per-WG; has_out uniform within WG so barriers are safe):
  if (has_out) {
    // out[NT-2] from the last window's red[.][6] (= r_{NT-2}·W_out)
    if (wave == 6) {
      float s = red[0][6][lane];
      #pragma unroll
      for (int w = 1; w < NWAVE; ++w) s += red[w][6][lane];
      out[(size_t)(NT - 2) * (NB * NO) + lane * NO + g] = s;
    }
    __syncthreads();
    // out[NT-1] from the final r (buffer NT&1), fresh after the last acquire
    const float* rm = r_m1 + (NT & 1) * NN * NB + k0 * NB + lane;
    float ao = 0.f;
    #pragma unroll
    for (int k = 0; k < KW; ++k) ao = fmaf(rm[k * NB], wo[k], ao);
    red[wave][6][lane] = ao;
    __syncthreads();
    if (wave == 6) {
      float t = red[0][6][lane];
      #pragma unroll
      for (int w = 1; w < NWAVE; ++w) t += red[w][6][lane];
      out[(size_t)(NT - 1) * (NB * NO) + lane * NO + g] = t;
    }
  }
}

extern "C" void kernel_launch(void* const* d_in, const int* in_sizes, int n_in,
                              void* d_out, int out_size, void* d_ws, size_t ws_size,
                              hipStream_t stream) {
  (void)in_sizes; (void)n_in; (void)out_size; (void)ws_size;
  const float* X         = (const float*)d_in[0];
  const float* W_rec_m1  = (const float*)d_in[1];
  const float* W_rec_pmd = (const float*)d_in[2];
  const float* W_rec_s1  = (const float*)d_in[3];
  const float* b_m1      = (const float*)d_in[4];
  const float* b_pmd     = (const float*)d_in[5];
  const float* b_s1      = (const float*)d_in[6];
  const float* W_pmd_m1  = (const float*)d_in[7];
  const float* W_s1_m1   = (const float*)d_in[8];
  const float* W_m1_pmd  = (const float*)d_in[9];
  const float* W_in_pmd  = (const float*)d_in[10];
  const float* W_in_s1   = (const float*)d_in[11];
  const float* W_out     = (const float*)d_in[12];
  float* out = (float*)d_out;

  float* wsf = (float*)d_ws;
  const float* XT = wsf + XT_OFF;
  float* XTw   = wsf + XT_OFF;
  float* r_m1  = wsf + RM_OFF;
  float* r_pmd = wsf + RP_OFF;
  float* r_s1  = wsf + RS_OFF;
  unsigned* flags = (unsigned*)(wsf + FLAG_OFF);
  unsigned* gen   = flags + 256 * 16;

  xpose_kernel<<<NT, 256, 0, stream>>>(X, XTw);

  void* args[19];
  args[0]  = (void*)&XT;
  args[1]  = (void*)&r_m1;  args[2]  = (void*)&r_pmd; args[3]  = (void*)&r_s1;
  args[4]  = (void*)&W_rec_m1; args[5] = (void*)&W_rec_pmd; args[6] = (void*)&W_rec_s1;
  args[7]  = (void*)&b_m1;  args[8]  = (void*)&b_pmd; args[9]  = (void*)&b_s1;
  args[10] = (void*)&W_pmd_m1; args[11] = (void*)&W_s1_m1; args[12] = (void*)&W_m1_pmd;
  args[13] = (void*)&W_in_pmd; args[14] = (void*)&W_in_s1; args[15] = (void*)&W_out;
  args[16] = (void*)&out;
  args[17] = (void*)&flags;
  args[18] = (void*)&gen;
  hipLaunchCooperativeKernel((const void*)rnn_kernel, dim3(NWG), dim3(1024), args, 0, stream);
}